// Round 6
// baseline (65.574 us; speedup 1.0000x reference)
//
#include <hip/hip_runtime.h>
#include <hip/hip_bf16.h>

typedef __attribute__((ext_vector_type(8))) short bf16x8;
typedef __attribute__((ext_vector_type(4))) float f32x4;

#define T_DIM 32
#define B_DIM 8192
#define S_DIM 256
#define H_DIM 128
#define BM    32              // batch rows per chunk
#define NCH   16              // chunks per block -> 512 rows/block
#define BLOCKS_PER_T 16
// grid = 32 t * 16 = 512 blocks = 2 per CU

__device__ __forceinline__ uint32_t cvt_pk_bf16(float lo, float hi) {
  uint32_t r;
  asm("v_cvt_pk_bf16_f32 %0, %1, %2" : "=v"(r) : "v"(lo), "v"(hi));
  return r;
}

// raw barrier: order LDS (lgkmcnt) but do NOT drain in-flight global loads
#define BARRIER() asm volatile("s_waitcnt lgkmcnt(0)\n\ts_barrier" ::: "memory")

// issue chunk (c)'s 8 non-temporal float4 loads (block-linear, fully coalesced)
#define ISSUE8(av, c)                                                          \
  _Pragma("unroll")                                                            \
  for (int j = 0; j < 8; ++j)                                                  \
    av[j] = __builtin_nontemporal_load(&A4[(size_t)(c) * 2048 + j * 256 + tid]);

// convert av (f32) -> bf16 into LDS buffer (XOR-swizzled rows)
#define CONVERT8(av, LDSBUF)                                                   \
  _Pragma("unroll")                                                            \
  for (int j = 0; j < 8; ++j) {                                                \
    const int f   = j * 256 + tid;                                             \
    const int row = f >> 6;                                                    \
    const int kq  = f & 63;                                                    \
    const uint32_t lo = cvt_pk_bf16(av[j].x, av[j].y);                         \
    const uint32_t hi = cvt_pk_bf16(av[j].z, av[j].w);                         \
    const int byteoff = (row * 512 + kq * 8) ^ ((row & 7) << 4);               \
    *reinterpret_cast<uint2*>(&(LDSBUF)[byteoff]) = make_uint2(lo, hi);        \
  }

// MFMA on 32 rows x this wave's 32 cols + fused SiLU epilogue -> red[RI]
#define MFMA_EPI(LDSBUF, RI)                                                   \
  {                                                                            \
    f32x4 acc[2][2];                                                           \
    _Pragma("unroll")                                                          \
    for (int mt = 0; mt < 2; ++mt) {                                           \
      acc[mt][0] = (f32x4){0.f, 0.f, 0.f, 0.f};                                \
      acc[mt][1] = (f32x4){0.f, 0.f, 0.f, 0.f};                                \
    }                                                                          \
    _Pragma("unroll")                                                          \
    for (int mt = 0; mt < 2; ++mt) {                                           \
      const int row = mt * 16 + l15;                                           \
      bf16x8 afr[8];                                                           \
      _Pragma("unroll")                                                        \
      for (int ks = 0; ks < 8; ++ks) {                                         \
        const int byteoff =                                                    \
            (row * 512 + ks * 64 + lg * 16) ^ ((row & 7) << 4);                \
        afr[ks] = *reinterpret_cast<const bf16x8*>(&(LDSBUF)[byteoff]);        \
      }                                                                        \
      _Pragma("unroll")                                                        \
      for (int ks = 0; ks < 8; ++ks) {                                         \
        acc[mt][0] = __builtin_amdgcn_mfma_f32_16x16x32_bf16(                  \
            afr[ks], bfr[0][ks], acc[mt][0], 0, 0, 0);                         \
        acc[mt][1] = __builtin_amdgcn_mfma_f32_16x16x32_bf16(                  \
            afr[ks], bfr[1][ks], acc[mt][1], 0, 0, 0);                         \
      }                                                                        \
    }                                                                          \
    _Pragma("unroll")                                                          \
    for (int mt = 0; mt < 2; ++mt) {                                           \
      float part[4];                                                           \
      _Pragma("unroll")                                                        \
      for (int r = 0; r < 4; ++r) {                                            \
        float s = 0.f;                                                         \
        _Pragma("unroll")                                                      \
        for (int nloc = 0; nloc < 2; ++nloc) {                                 \
          const float h   = acc[mt][nloc][r] + b1c[nloc];                      \
          const float sig = 1.f / (1.f + __expf(-h));                          \
          s += h * sig * w2c[nloc];                                            \
        }                                                                      \
        s += __shfl_xor(s, 1);                                                 \
        s += __shfl_xor(s, 2);                                                 \
        s += __shfl_xor(s, 4);                                                 \
        s += __shfl_xor(s, 8);                                                 \
        part[r] = s;                                                           \
      }                                                                        \
      if (l15 == 0) {                                                          \
        _Pragma("unroll")                                                      \
        for (int r = 0; r < 4; ++r)                                            \
          red[RI][wid][mt * 16 + lg * 4 + r] = part[r];                        \
      }                                                                        \
    }                                                                          \
  }

#define OUTW(RI, cc)                                                           \
  if (tid < BM) {                                                              \
    const float o = red[RI][0][tid] + red[RI][1][tid] + red[RI][2][tid] +      \
                    red[RI][3][tid] + b2t;                                     \
    __builtin_nontemporal_store(o, &outw[(cc) * BM + tid]);                    \
  }

__global__ __launch_bounds__(256, 2) void cvar_mlp_kernel(
    const float* __restrict__ states, const float* __restrict__ W1,
    const float* __restrict__ b1, const float* __restrict__ W2,
    const float* __restrict__ b2, float* __restrict__ out)
{
  // double-buffered 32x256 bf16 states tile (row stride 512B, XOR-swizzled)
  __shared__ __align__(16) char ldsA[2][BM * 512];   // 2 x 16 KB
  __shared__ float red[2][4][BM];

  const int tid  = threadIdx.x;
  const int wid  = tid >> 6;
  const int lane = tid & 63;
  const int l15  = lane & 15;
  const int lg   = lane >> 4;          // 0..3

  // XCD-grouped: blocks with same (bidx&7) share a t-range -> W1[t] L2-local
  const int bidx = blockIdx.x;         // 0..511
  const int xcd  = bidx & 7;
  const int slot = bidx >> 3;          // 0..63
  const int t    = xcd * 4 + (slot >> 4);
  const int cg   = slot & 15;
  const int b0   = cg * (BM * NCH);    // 512 rows per block

  const float* Ag  = states + ((size_t)t * B_DIM + b0) * S_DIM;
  const f32x4* A4  = reinterpret_cast<const f32x4*>(Ag);
  const float* W1g = W1 + (size_t)t * (S_DIM * H_DIM);
  float*      outw = out + (size_t)t * B_DIM + b0;

  // ---- prologue: start the stream (chunks 0 and 1 in flight) ----
  f32x4 avA[8], avB[8];
  ISSUE8(avA, 0);
  ISSUE8(avB, 1);

  // ---- W1 fragment preload into registers (L2; amortized over 16 chunks) ----
  // B-frag for mfma_f32_16x16x32_bf16: lane holds col n=lane&15, k=ks*32+lg*8+j
  bf16x8 bfr[2][8];
#pragma unroll
  for (int nloc = 0; nloc < 2; ++nloc) {
    const int ncol = (wid * 2 + nloc) * 16 + l15;
#pragma unroll
    for (int ks = 0; ks < 8; ++ks) {
      const int kbase = ks * 32 + lg * 8;
      float e[8];
#pragma unroll
      for (int j = 0; j < 8; ++j)
        e[j] = W1g[(size_t)(kbase + j) * H_DIM + ncol];
      union { uint32_t u[4]; bf16x8 v; } uu;
      uu.u[0] = cvt_pk_bf16(e[0], e[1]);
      uu.u[1] = cvt_pk_bf16(e[2], e[3]);
      uu.u[2] = cvt_pk_bf16(e[4], e[5]);
      uu.u[3] = cvt_pk_bf16(e[6], e[7]);
      bfr[nloc][ks] = uu.v;
    }
  }

  float b1c[2], w2c[2];
#pragma unroll
  for (int nloc = 0; nloc < 2; ++nloc) {
    const int col = (wid * 2 + nloc) * 16 + l15;
    b1c[nloc] = b1[(size_t)t * H_DIM + col];
    w2c[nloc] = W2[(size_t)t * H_DIM + col];
  }
  const float b2t = b2[t];

  // convert chunk 0, refill its slot with chunk 2 -> always >=8 loads in flight
  CONVERT8(avA, ldsA[0]);
  ISSUE8(avA, 2);
  BARRIER();

  // ---- main loop, manually 2x unrolled (static register-array indexing) ----
#pragma unroll 1
  for (int c = 0; c < NCH; c += 2) {
    // even iteration: compute chunk c from ldsA[0]
    MFMA_EPI(ldsA[0], 0);
    if (c + 1 < NCH) {
      CONVERT8(avB, ldsA[1]);          // waits avB (c+1); avA (c+2) in flight
      if (c + 3 < NCH) ISSUE8(avB, c + 3);
    }
    BARRIER();
    OUTW(0, c);

    // odd iteration: compute chunk c+1 from ldsA[1]
    MFMA_EPI(ldsA[1], 1);
    if (c + 2 < NCH) {
      CONVERT8(avA, ldsA[0]);          // waits avA (c+2); avB (c+3) in flight
      if (c + 4 < NCH) ISSUE8(avA, c + 4);
    }
    BARRIER();
    OUTW(1, c + 1);
  }
}

extern "C" void kernel_launch(void* const* d_in, const int* in_sizes, int n_in,
                              void* d_out, int out_size, void* d_ws, size_t ws_size,
                              hipStream_t stream) {
  const float* states = (const float*)d_in[0];
  const float* W1     = (const float*)d_in[1];
  const float* b1     = (const float*)d_in[2];
  const float* W2     = (const float*)d_in[3];
  const float* b2     = (const float*)d_in[4];
  float* out          = (float*)d_out;

  const int grid = T_DIM * BLOCKS_PER_T;   // 512
  cvar_mlp_kernel<<<grid, 256, 0, stream>>>(states, W1, b1, W2, b2, out);
}